// Round 7
// baseline (364.282 us; speedup 1.0000x reference)
//
#include <hip/hip_runtime.h>
#include <hip/hip_bf16.h>
#include <stdint.h>

#define DIN 128
#define DOUT 32
#define NREP 64
#define BKT_SHIFT 9
#define BKT_NODES 512
#define MAXBE 12288

typedef unsigned int uint;
typedef float f32x4 __attribute__((ext_vector_type(4)));
typedef _Float16 f16x8 __attribute__((ext_vector_type(8)));

__device__ __forceinline__ float frelu(float x) { return x > 0.f ? x : 0.f; }

__device__ __forceinline__ void wred(f32x4& v, int d) {
    v.x += __shfl_down(v.x, d);
    v.y += __shfl_down(v.y, d);
    v.z += __shfl_down(v.z, d);
    v.w += __shfl_down(v.w, d);
}

// ---------------- K0: zero bucket counts + stat accumulators ----------------
__global__ void k_zero(uint* __restrict__ bcnt, int nb, float* __restrict__ stats, int nstats) {
    int i = blockIdx.x * blockDim.x + threadIdx.x;
    if (i < nb) bcnt[i] = 0u;
    else if (i < nb + nstats) stats[i - nb] = 0.f;
}

// ---------------- K1: bucket histogram (dst>>9) ----------------
__global__ __launch_bounds__(256) void k_bhist(const int* __restrict__ dst,
                                               uint* __restrict__ bcnt, int E, int nbuck) {
    __shared__ uint lh[256];
    const int t = threadIdx.x;
    lh[t] = 0;
    __syncthreads();
    const int base = blockIdx.x * 8192;
#pragma unroll 8
    for (int i = 0; i < 32; ++i) {
        int e = base + t + 256 * i;
        if (e < E) atomicAdd(&lh[((uint)__builtin_nontemporal_load(&dst[e])) >> BKT_SHIFT], 1u);
    }
    __syncthreads();
    if (t < nbuck && lh[t]) atomicAdd(&bcnt[t], lh[t]);
}

// ---------------- K2: scan bucket counts -> boff, gcur ----------------
__global__ __launch_bounds__(256) void k_bscan(const uint* __restrict__ bcnt,
                                               uint* __restrict__ boff, uint* __restrict__ gcur,
                                               int nbuck, int E) {
    __shared__ uint ps[256];
    const int t = threadIdx.x;
    uint v = (t < nbuck) ? bcnt[t] : 0u;
    ps[t] = v;
    __syncthreads();
    for (int o = 1; o < 256; o <<= 1) {
        uint u = (t >= o) ? ps[t - o] : 0u;
        __syncthreads();
        ps[t] += u;
        __syncthreads();
    }
    if (t < nbuck) {
        uint ex = ps[t] - v;
        boff[t] = ex;
        gcur[t] = ex;
    }
    if (t == 0) boff[nbuck] = (uint)E;
}

// ---------------- K3: partition edges into bucket-contiguous packed array ----------------
__global__ __launch_bounds__(256) void k_part(const int* __restrict__ src,
                                              const int* __restrict__ dst,
                                              uint* __restrict__ gcur, uint* __restrict__ gbuf,
                                              int E, int nbuck) {
    __shared__ uint lh[256], lb[256], lc[256];
    const int t = threadIdx.x;
    lh[t] = 0;
    lc[t] = 0;
    __syncthreads();
    const int base = blockIdx.x * 8192;
#pragma unroll 8
    for (int i = 0; i < 32; ++i) {
        int e = base + t + 256 * i;
        if (e < E) atomicAdd(&lh[((uint)__builtin_nontemporal_load(&dst[e])) >> BKT_SHIFT], 1u);
    }
    __syncthreads();
    if (t < nbuck && lh[t]) lb[t] = atomicAdd(&gcur[t], lh[t]);
    __syncthreads();
#pragma unroll 8
    for (int i = 0; i < 32; ++i) {
        int e = base + t + 256 * i;
        if (e < E) {
            uint d = (uint)__builtin_nontemporal_load(&dst[e]);
            uint s = (uint)__builtin_nontemporal_load(&src[e]);
            uint b = d >> BKT_SHIFT;
            uint r = atomicAdd(&lc[b], 1u);
            gbuf[lb[b] + r] = ((d & (BKT_NODES - 1)) << 17) | s;
        }
    }
}

// ---------------- K4: per-bucket local CSR: off + esrc ----------------
__global__ __launch_bounds__(256) void k_csr(const uint* __restrict__ boff,
                                             const uint* __restrict__ gbuf,
                                             uint* __restrict__ off, uint* __restrict__ esrc,
                                             int N, int E, int nbuck) {
    __shared__ uint ed[MAXBE];
    __shared__ uint lh[BKT_NODES];
    __shared__ uint lsc[BKT_NODES];
    __shared__ uint ps[256];
    const int b = blockIdx.x, t = threadIdx.x;
    const uint bb = boff[b];
    int cnt = (int)(boff[b + 1] - bb);
    if (cnt > MAXBE) cnt = MAXBE;
    for (int i = t; i < cnt; i += 256) ed[i] = __builtin_nontemporal_load(&gbuf[bb + i]);
    lh[t] = 0;
    lh[t + 256] = 0;
    __syncthreads();
    for (int i = t; i < cnt; i += 256) atomicAdd(&lh[ed[i] >> 17], 1u);
    __syncthreads();
    const uint v0 = lh[2 * t], v1 = lh[2 * t + 1];
    ps[t] = v0 + v1;
    __syncthreads();
    for (int o = 1; o < 256; o <<= 1) {
        uint u = (t >= o) ? ps[t - o] : 0u;
        __syncthreads();
        ps[t] += u;
        __syncthreads();
    }
    const uint ex = ps[t] - (v0 + v1);
    lsc[2 * t] = ex;
    lsc[2 * t + 1] = ex + v0;
    const int n0 = b << BKT_SHIFT;
    if (n0 + 2 * t < N) off[n0 + 2 * t] = bb + ex;
    if (n0 + 2 * t + 1 < N) off[n0 + 2 * t + 1] = bb + ex + v0;
    if (b == nbuck - 1 && t == 0) off[N] = (uint)E;
    __syncthreads();
    for (int i = t; i < cnt; i += 256) {
        uint p = ed[i];
        uint r = atomicAdd(&lsc[p >> 17], 1u);
        esrc[bb + r] = p & 0x1FFFFu;
    }
}

// ---------------- K5: transpose+convert weights to fp16 Bt[outcol][k] ----------------
__global__ void k_prepw(const float* __restrict__ Wrel1, const float* __restrict__ Wroot1,
                        const float* __restrict__ Wrel2, const float* __restrict__ Wroot2,
                        _Float16* __restrict__ Bt1, _Float16* __restrict__ Bt2) {
    const int c = blockIdx.x;
    const int k = threadIdx.x;
    if (c < 256) {
        const float* W = (c < 128) ? Wrel1 : Wroot1;
        int cl = c & 127;
        Bt1[c * 128 + k] = (_Float16)W[k * 128 + cl];
    } else {
        int c2 = c - 256;
        const float* W = (c2 < 32) ? Wrel2 : Wroot2;
        int cl = c2 & 31;
        Bt2[c2 * 128 + k] = (_Float16)W[k * 32 + cl];
    }
}

// ---------------- MFMA GEMM ----------------
// PANEL_OUT: Y/Z stored as 16-col panels [c>>4][N][16] (GEMM1).
// NORM (GEMM2): A is fp16 in panel layout, BN+relu fused on load; outputs row-major.
template <int WC, bool NORM, bool PANEL_OUT, typename AT>
__global__ __launch_bounds__(256) void k_gemm(
    const AT* __restrict__ A, const _Float16* __restrict__ Bt,
    const float* __restrict__ bias,
    const float* __restrict__ mean, const float* __restrict__ inv,
    const float* __restrict__ gamma, const float* __restrict__ beta,
    _Float16* __restrict__ Y, _Float16* __restrict__ Z, int N) {
    __shared__ __align__(16) char smem[32768];
    const int tid = threadIdx.x;
    const int rowBase = blockIdx.x * 64;
    const int colBase = blockIdx.y * 64;

    if constexpr (!NORM) {
#pragma unroll
        for (int i = 0; i < 8; ++i) {
            int f = tid + 256 * i;
            int row = f >> 5, c4 = f & 31;
            int grow = rowBase + row;
            float4 v = make_float4(0.f, 0.f, 0.f, 0.f);
            if (grow < N) v = *(const float4*)&((const float*)A)[(size_t)grow * DIN + c4 * 4];
            union { short4 s; _Float16 h[4]; } u;
            u.h[0] = (_Float16)v.x; u.h[1] = (_Float16)v.y;
            u.h[2] = (_Float16)v.z; u.h[3] = (_Float16)v.w;
            int off = row * 256 + ((c4 * 8) ^ ((row & 7) << 4));
            *(short4*)(smem + off) = u.s;
        }
    } else {
#pragma unroll
        for (int i = 0; i < 4; ++i) {
            int f = tid + 256 * i;
            int row = f >> 4, sl = f & 15;
            int grow = rowBase + row;
            f16x8 hv = {};
            if (grow < N) {
                // panel A read: col sl*8 -> panel sl>>1, offset (sl&1)*8
                const _Float16* Ap = (const _Float16*)A;
                f16x8 a = *(const f16x8*)&Ap[((size_t)(sl >> 1) * N + grow) * 16 + (sl & 1) * 8];
                int k = sl * 8;
                f32x4 m0 = *(const f32x4*)&mean[k],  m1 = *(const f32x4*)&mean[k + 4];
                f32x4 i0 = *(const f32x4*)&inv[k],   i1 = *(const f32x4*)&inv[k + 4];
                f32x4 g0 = *(const f32x4*)&gamma[k], g1 = *(const f32x4*)&gamma[k + 4];
                f32x4 b0 = *(const f32x4*)&beta[k],  b1 = *(const f32x4*)&beta[k + 4];
#pragma unroll
                for (int j = 0; j < 4; ++j) {
                    float v = frelu(((float)a[j] - m0[j]) * i0[j] * g0[j] + b0[j]);
                    hv[j] = (_Float16)v;
                }
#pragma unroll
                for (int j = 0; j < 4; ++j) {
                    float v = frelu(((float)a[4 + j] - m1[j]) * i1[j] * g1[j] + b1[j]);
                    hv[4 + j] = (_Float16)v;
                }
            }
            int off = row * 256 + ((sl * 16) ^ ((row & 7) << 4));
            *(f16x8*)(smem + off) = hv;
        }
    }
#pragma unroll
    for (int i = 0; i < 4; ++i) {
        int f = tid + 256 * i;
        int row = f >> 4, sl = f & 15;
        f16x8 v = *(const f16x8*)&Bt[(size_t)(colBase + row) * 128 + sl * 8];
        int off = row * 256 + ((sl * 16) ^ ((row & 7) << 4));
        *(f16x8*)(smem + 16384 + off) = v;
    }
    __syncthreads();

    const int lane = tid & 63;
    const int w = tid >> 6;
    const int wrow = (w >> 1) * 32;
    const int wcol = (w & 1) * 32;
    const int lr = lane & 15;
    const int lk = lane >> 4;

    f32x4 acc[2][2] = {};
#pragma unroll
    for (int s = 0; s < 4; ++s) {
        f16x8 a[2], b[2];
#pragma unroll
        for (int m = 0; m < 2; ++m) {
            int row = wrow + m * 16 + lr;
            int off = row * 256 + (((s * 64) + lk * 16) ^ ((row & 7) << 4));
            a[m] = *(const f16x8*)(smem + off);
        }
#pragma unroll
        for (int n = 0; n < 2; ++n) {
            int col = wcol + n * 16 + lr;
            int off = col * 256 + (((s * 64) + lk * 16) ^ ((col & 7) << 4));
            b[n] = *(const f16x8*)(smem + 16384 + off);
        }
#pragma unroll
        for (int m = 0; m < 2; ++m)
#pragma unroll
            for (int n = 0; n < 2; ++n)
                acc[m][n] = __builtin_amdgcn_mfma_f32_16x16x32_f16(a[m], b[n], acc[m][n], 0, 0, 0);
    }

    __syncthreads();
    float* Cs = (float*)smem;
#pragma unroll
    for (int m = 0; m < 2; ++m)
#pragma unroll
        for (int n = 0; n < 2; ++n) {
            int r0 = wrow + m * 16 + (lane >> 4) * 4;
            int c = wcol + n * 16 + (lane & 15);
#pragma unroll
            for (int j = 0; j < 4; ++j) Cs[(r0 + j) * 68 + c] = acc[m][n][j];
        }
    __syncthreads();

    {
        int row = tid >> 2, cq = tid & 3;
        int grow = rowBase + row;
        if (grow < N) {
            const int cb = row * 68 + cq * 16;
            f32x4 t0 = *(const f32x4*)&Cs[cb + 0];
            f32x4 t1 = *(const f32x4*)&Cs[cb + 4];
            f32x4 t2 = *(const f32x4*)&Cs[cb + 8];
            f32x4 t3 = *(const f32x4*)&Cs[cb + 12];
            int gc0 = colBase + cq * 16;
            _Float16* dstp;
            int dcol;
            if (gc0 < WC) {
                dstp = Y; dcol = gc0;
            } else {
                dstp = Z; dcol = gc0 - WC;
                f32x4 b0 = *(const f32x4*)&bias[dcol + 0];
                f32x4 b1 = *(const f32x4*)&bias[dcol + 4];
                f32x4 b2 = *(const f32x4*)&bias[dcol + 8];
                f32x4 b3 = *(const f32x4*)&bias[dcol + 12];
                t0 += b0; t1 += b1; t2 += b2; t3 += b3;
            }
            f16x8 h0, h1;
            h0[0] = (_Float16)t0.x; h0[1] = (_Float16)t0.y; h0[2] = (_Float16)t0.z; h0[3] = (_Float16)t0.w;
            h0[4] = (_Float16)t1.x; h0[5] = (_Float16)t1.y; h0[6] = (_Float16)t1.z; h0[7] = (_Float16)t1.w;
            h1[0] = (_Float16)t2.x; h1[1] = (_Float16)t2.y; h1[2] = (_Float16)t2.z; h1[3] = (_Float16)t2.w;
            h1[4] = (_Float16)t3.x; h1[5] = (_Float16)t3.y; h1[6] = (_Float16)t3.z; h1[7] = (_Float16)t3.w;
            if constexpr (PANEL_OUT) {
                _Float16* pb = dstp + ((size_t)(dcol >> 4) * N + grow) * 16;
                *(f16x8*)&pb[0] = h0;
                *(f16x8*)&pb[8] = h1;
            } else {
                *(f16x8*)&dstp[(size_t)grow * WC + dcol] = h0;
                *(f16x8*)&dstp[(size_t)grow * WC + dcol + 8] = h1;
            }
        }
    }
}

// ---------------- Panel aggregation (layer 1): XCD-local gathers ----------------
// y,z,h in panel layout [8][N][16] fp16. Block: panel g = bid&7, 128 nodes, 2 thr/node.
__global__ __launch_bounds__(256) void k_aggp(
    const _Float16* __restrict__ y, const _Float16* z, _Float16* h,
    const uint* __restrict__ off, const uint* __restrict__ esrc,
    float* __restrict__ gstat, int N) {
    const int g = blockIdx.x & 7;
    const int nb = blockIdx.x >> 3;
    const int tid = threadIdx.x;
    const int hf = tid & 1;
    const int n = nb * 128 + (tid >> 1);
    const _Float16* yp = y + (size_t)g * N * 16 + hf * 8;
    const _Float16* zp = z + (size_t)g * N * 16 + hf * 8;
    _Float16* hp = h + (size_t)g * N * 16 + hf * 8;

    float hv[8] = {0, 0, 0, 0, 0, 0, 0, 0};
    if (n < N) {
        const uint beg = off[n], end = off[n + 1];
        float acc[8] = {0, 0, 0, 0, 0, 0, 0, 0};
        uint e = beg;
        for (; e + 4 <= end; e += 4) {
            const uint s0 = esrc[e], s1 = esrc[e + 1];
            const uint s2 = esrc[e + 2], s3 = esrc[e + 3];
            const f16x8 a0 = *(const f16x8*)&yp[(size_t)s0 * 16];
            const f16x8 a1 = *(const f16x8*)&yp[(size_t)s1 * 16];
            const f16x8 a2 = *(const f16x8*)&yp[(size_t)s2 * 16];
            const f16x8 a3 = *(const f16x8*)&yp[(size_t)s3 * 16];
#pragma unroll
            for (int j = 0; j < 8; ++j)
                acc[j] += ((float)a0[j] + (float)a1[j]) + ((float)a2[j] + (float)a3[j]);
        }
        for (; e < end; ++e) {
            const uint s0 = esrc[e];
            const f16x8 a0 = *(const f16x8*)&yp[(size_t)s0 * 16];
#pragma unroll
            for (int j = 0; j < 8; ++j) acc[j] += (float)a0[j];
        }
        const f16x8 zz = __builtin_nontemporal_load((const f16x8*)&zp[(size_t)n * 16]);
        f16x8 hs;
#pragma unroll
        for (int j = 0; j < 8; ++j) {
            hv[j] = acc[j] + (float)zz[j];
            hs[j] = (_Float16)hv[j];
        }
        __builtin_nontemporal_store(hs, (f16x8*)&hp[(size_t)n * 16]);
    }

    // stats: wave shuffle reduce (stride-2 lanes share cols), then tiny LDS combine
    f32x4 sA = {hv[0], hv[1], hv[2], hv[3]};
    f32x4 sB = {hv[4], hv[5], hv[6], hv[7]};
    f32x4 qA = {hv[0] * hv[0], hv[1] * hv[1], hv[2] * hv[2], hv[3] * hv[3]};
    f32x4 qB = {hv[4] * hv[4], hv[5] * hv[5], hv[6] * hv[6], hv[7] * hv[7]};
#pragma unroll
    for (int d = 32; d >= 2; d >>= 1) {
        wred(sA, d); wred(sB, d); wred(qA, d); wred(qB, d);
    }
    __shared__ f32x4 sred[4][2][4];
    const int w = tid >> 6, lane = tid & 63;
    if (lane < 2) {
        sred[w][lane][0] = sA; sred[w][lane][1] = sB;
        sred[w][lane][2] = qA; sred[w][lane][3] = qB;
    }
    __syncthreads();
    if (tid < 2) {
        f32x4 SA = sred[0][tid][0] + sred[1][tid][0] + sred[2][tid][0] + sred[3][tid][0];
        f32x4 SB = sred[0][tid][1] + sred[1][tid][1] + sred[2][tid][1] + sred[3][tid][1];
        f32x4 QA = sred[0][tid][2] + sred[1][tid][2] + sred[2][tid][2] + sred[3][tid][2];
        f32x4 QB = sred[0][tid][3] + sred[1][tid][3] + sred[2][tid][3] + sred[3][tid][3];
        float* gs = gstat + (nb & (NREP - 1)) * (2 * DIN);
        const int cb = g * 16 + tid * 8;
        unsafeAtomicAdd(&gs[cb + 0], SA.x);
        unsafeAtomicAdd(&gs[cb + 1], SA.y);
        unsafeAtomicAdd(&gs[cb + 2], SA.z);
        unsafeAtomicAdd(&gs[cb + 3], SA.w);
        unsafeAtomicAdd(&gs[cb + 4], SB.x);
        unsafeAtomicAdd(&gs[cb + 5], SB.y);
        unsafeAtomicAdd(&gs[cb + 6], SB.z);
        unsafeAtomicAdd(&gs[cb + 7], SB.w);
        unsafeAtomicAdd(&gs[DIN + cb + 0], QA.x);
        unsafeAtomicAdd(&gs[DIN + cb + 1], QA.y);
        unsafeAtomicAdd(&gs[DIN + cb + 2], QA.z);
        unsafeAtomicAdd(&gs[DIN + cb + 3], QA.w);
        unsafeAtomicAdd(&gs[DIN + cb + 4], QB.x);
        unsafeAtomicAdd(&gs[DIN + cb + 5], QB.y);
        unsafeAtomicAdd(&gs[DIN + cb + 6], QB.z);
        unsafeAtomicAdd(&gs[DIN + cb + 7], QB.w);
    }
}

// ---------------- Row-major aggregation (layer 2) ----------------
template <int DIMS, int IT>
__global__ __launch_bounds__(256) void k_agg(
    const _Float16* __restrict__ y, const _Float16* z, _Float16* h,
    const uint* __restrict__ off, const uint* __restrict__ esrc,
    float* __restrict__ gstat, int N) {
    constexpr int TPN = DIMS / 8;
    constexpr int G = 256 / TPN;
    const int tid = threadIdx.x;
    const int c8 = tid & (TPN - 1);
    const int g = tid / TPN;
    const int col0 = c8 * 8;
    const int base = blockIdx.x * (G * IT);
    float ssum[8] = {0, 0, 0, 0, 0, 0, 0, 0};
    float ssq[8] = {0, 0, 0, 0, 0, 0, 0, 0};

    for (int it = 0; it < IT; ++it) {
        const int n = base + it * G + g;
        if (n < N) {
            const uint beg = off[n], end = off[n + 1];
            float acc[8] = {0, 0, 0, 0, 0, 0, 0, 0};
            uint e = beg;
            for (; e + 4 <= end; e += 4) {
                const uint s0 = esrc[e], s1 = esrc[e + 1];
                const uint s2 = esrc[e + 2], s3 = esrc[e + 3];
                const f16x8 a0 = *(const f16x8*)&y[(size_t)s0 * DIMS + col0];
                const f16x8 a1 = *(const f16x8*)&y[(size_t)s1 * DIMS + col0];
                const f16x8 a2 = *(const f16x8*)&y[(size_t)s2 * DIMS + col0];
                const f16x8 a3 = *(const f16x8*)&y[(size_t)s3 * DIMS + col0];
#pragma unroll
                for (int j = 0; j < 8; ++j)
                    acc[j] += ((float)a0[j] + (float)a1[j]) + ((float)a2[j] + (float)a3[j]);
            }
            for (; e < end; ++e) {
                const uint s0 = esrc[e];
                const f16x8 a0 = *(const f16x8*)&y[(size_t)s0 * DIMS + col0];
#pragma unroll
                for (int j = 0; j < 8; ++j) acc[j] += (float)a0[j];
            }
            const size_t idx = (size_t)n * DIMS + col0;
            const f16x8 zz = __builtin_nontemporal_load((const f16x8*)&z[idx]);
            float hv[8];
            f16x8 hs;
#pragma unroll
            for (int j = 0; j < 8; ++j) {
                hv[j] = acc[j] + (float)zz[j];
                hs[j] = (_Float16)hv[j];
            }
            __builtin_nontemporal_store(hs, (f16x8*)&h[idx]);
#pragma unroll
            for (int j = 0; j < 8; ++j) {
                ssum[j] += hv[j];
                ssq[j] += hv[j] * hv[j];
            }
        }
    }

    __shared__ f32x4 redA[256], redB[256], redC[256], redD[256];
    redA[tid] = (f32x4){ssum[0], ssum[1], ssum[2], ssum[3]};
    redB[tid] = (f32x4){ssum[4], ssum[5], ssum[6], ssum[7]};
    redC[tid] = (f32x4){ssq[0], ssq[1], ssq[2], ssq[3]};
    redD[tid] = (f32x4){ssq[4], ssq[5], ssq[6], ssq[7]};
    __syncthreads();
    for (int st = G / 2; st >= 1; st >>= 1) {
        if (g < st) {
            redA[tid] += redA[tid + st * TPN];
            redB[tid] += redB[tid + st * TPN];
            redC[tid] += redC[tid + st * TPN];
            redD[tid] += redD[tid + st * TPN];
        }
        __syncthreads();
    }
    if (g == 0) {
        float* gs = gstat + (blockIdx.x & (NREP - 1)) * (2 * DIMS);
        f32x4 s0 = redA[c8], s1 = redB[c8], q0 = redC[c8], q1 = redD[c8];
        unsafeAtomicAdd(&gs[col0 + 0], s0.x);
        unsafeAtomicAdd(&gs[col0 + 1], s0.y);
        unsafeAtomicAdd(&gs[col0 + 2], s0.z);
        unsafeAtomicAdd(&gs[col0 + 3], s0.w);
        unsafeAtomicAdd(&gs[col0 + 4], s1.x);
        unsafeAtomicAdd(&gs[col0 + 5], s1.y);
        unsafeAtomicAdd(&gs[col0 + 6], s1.z);
        unsafeAtomicAdd(&gs[col0 + 7], s1.w);
        unsafeAtomicAdd(&gs[DIMS + col0 + 0], q0.x);
        unsafeAtomicAdd(&gs[DIMS + col0 + 1], q0.y);
        unsafeAtomicAdd(&gs[DIMS + col0 + 2], q0.z);
        unsafeAtomicAdd(&gs[DIMS + col0 + 3], q0.w);
        unsafeAtomicAdd(&gs[DIMS + col0 + 4], q1.x);
        unsafeAtomicAdd(&gs[DIMS + col0 + 5], q1.y);
        unsafeAtomicAdd(&gs[DIMS + col0 + 6], q1.z);
        unsafeAtomicAdd(&gs[DIMS + col0 + 7], q1.w);
    }
}

// ---------------- finalize BN stats from NREP replicas ----------------
__global__ void k_finalize(const float* __restrict__ rep, float* __restrict__ mean,
                           float* __restrict__ inv, int C, float invN) {
    int c = threadIdx.x;
    if (c < C) {
        float s = 0.f, q = 0.f;
        for (int r = 0; r < NREP; ++r) {
            s += rep[r * 2 * C + c];
            q += rep[r * 2 * C + C + c];
        }
        float m = s * invN;
        float v = q * invN - m * m;
        mean[c] = m;
        inv[c] = rsqrtf(v + 1e-5f);
    }
}

// ---------------- final BN+relu elementwise (h2 fp16 row-major -> out fp32) ----------------
__global__ void k_out(const _Float16* __restrict__ h2, const float* __restrict__ mean,
                      const float* __restrict__ inv, const float* __restrict__ gamma,
                      const float* __restrict__ beta, float* __restrict__ out, int nch) {
    int i = blockIdx.x * blockDim.x + threadIdx.x;
    if (i < nch) {
        int c = (i & 3) * 8;
        f16x8 hv = *(const f16x8*)&h2[(size_t)i * 8];
        f32x4 m0 = *(const f32x4*)&mean[c],  m1 = *(const f32x4*)&mean[c + 4];
        f32x4 i0 = *(const f32x4*)&inv[c],   i1 = *(const f32x4*)&inv[c + 4];
        f32x4 g0 = *(const f32x4*)&gamma[c], g1 = *(const f32x4*)&gamma[c + 4];
        f32x4 b0 = *(const f32x4*)&beta[c],  b1 = *(const f32x4*)&beta[c + 4];
        f32x4 o0, o1;
#pragma unroll
        for (int j = 0; j < 4; ++j) o0[j] = frelu(((float)hv[j] - m0[j]) * i0[j] * g0[j] + b0[j]);
#pragma unroll
        for (int j = 0; j < 4; ++j) o1[j] = frelu(((float)hv[4 + j] - m1[j]) * i1[j] * g1[j] + b1[j]);
        *(f32x4*)&out[(size_t)i * 8] = o0;
        *(f32x4*)&out[(size_t)i * 8 + 4] = o1;
    }
}

extern "C" void kernel_launch(void* const* d_in, const int* in_sizes, int n_in,
                              void* d_out, int out_size, void* d_ws, size_t ws_size,
                              hipStream_t stream) {
    const float* x      = (const float*)d_in[0];
    const int*   eidx   = (const int*)d_in[1];
    const float* Wrel1  = (const float*)d_in[2];
    const float* brel1  = (const float*)d_in[3];
    const float* Wroot1 = (const float*)d_in[4];
    const float* gamma1 = (const float*)d_in[5];
    const float* beta1  = (const float*)d_in[6];
    const float* Wrel2  = (const float*)d_in[7];
    const float* brel2  = (const float*)d_in[8];
    const float* Wroot2 = (const float*)d_in[9];
    const float* gamma2 = (const float*)d_in[10];
    const float* beta2  = (const float*)d_in[11];

    const int N = in_sizes[0] / DIN;
    const int E = in_sizes[1] / 2;
    const int* src = eidx;
    const int* dst = eidx + E;
    const int nbuck = (N + BKT_NODES - 1) >> BKT_SHIFT;

    char* p = (char*)d_ws;
    auto alloc = [&](size_t bytes) {
        void* r = (void*)p;
        p += (bytes + 255) & ~(size_t)255;
        return r;
    };
    uint*      bcnt = (uint*)alloc(256 * 4);
    uint*      boff = (uint*)alloc(257 * 4);
    uint*      gcur = (uint*)alloc(256 * 4);
    uint*      gbuf = (uint*)alloc((size_t)E * 4);
    uint*      esrc = (uint*)alloc((size_t)E * 4);
    uint*      off  = (uint*)alloc((size_t)(N + 1) * 4);
    _Float16*  Bt1  = (_Float16*)alloc(256 * 128 * 2);
    _Float16*  Bt2  = (_Float16*)alloc(64 * 128 * 2);
    _Float16*  y1   = (_Float16*)alloc((size_t)N * DIN * 2);   // panel [8][N][16]
    _Float16*  z1   = (_Float16*)alloc((size_t)N * DIN * 2);   // panel; h1 aliases z1
    _Float16*  y2   = (_Float16*)alloc((size_t)N * DOUT * 2);  // row-major
    _Float16*  z2   = (_Float16*)alloc((size_t)N * DOUT * 2);  // row-major; h2 aliases z2
    float*     stats = (float*)alloc((size_t)(NREP * 2 * DIN + NREP * 2 * DOUT + 2 * DIN + 2 * DOUT) * 4);
    float* s1rep = stats;
    float* s2rep = stats + NREP * 2 * DIN;
    float* mean1 = s2rep + NREP * 2 * DOUT;
    float* inv1  = mean1 + DIN;
    float* mean2 = inv1 + DIN;
    float* inv2  = mean2 + DOUT;

    const float invN = 1.f / (float)N;
    const int nstats = NREP * 2 * DIN + NREP * 2 * DOUT;
    const int nbE = (E + 8191) / 8192;
    const int nb64 = (N + 63) / 64;

    int nz = 256 + nstats;
    k_zero<<<(nz + 255) / 256, 256, 0, stream>>>(bcnt, 256, stats, nstats);
    k_bhist<<<nbE, 256, 0, stream>>>(dst, bcnt, E, nbuck);
    k_bscan<<<1, 256, 0, stream>>>(bcnt, boff, gcur, nbuck, E);
    k_part<<<nbE, 256, 0, stream>>>(src, dst, gcur, gbuf, E, nbuck);
    k_csr<<<nbuck, 256, 0, stream>>>(boff, gbuf, off, esrc, N, E, nbuck);
    k_prepw<<<320, 128, 0, stream>>>(Wrel1, Wroot1, Wrel2, Wroot2, Bt1, Bt2);

    // GEMM1: y1,z1 panel fp16
    k_gemm<DIN, false, true, float><<<dim3(nb64, 4), 256, 0, stream>>>(
        x, Bt1, brel1, nullptr, nullptr, nullptr, nullptr, y1, z1, N);
    // agg1 (panel, XCD-local) + stats
    {
        int nbNode = (N + 127) / 128;
        k_aggp<<<nbNode * 8, 256, 0, stream>>>(y1, z1, z1, off, esrc, s1rep, N);
    }
    k_finalize<<<1, DIN, 0, stream>>>(s1rep, mean1, inv1, DIN, invN);
    // GEMM2: panel A in, row-major out
    k_gemm<DOUT, true, false, _Float16><<<dim3(nb64, 1), 256, 0, stream>>>(
        z1, Bt2, brel2, mean1, inv1, gamma1, beta1, y2, z2, N);
    // agg2 + stats (row-major)
    k_agg<DOUT, 1><<<(N + 63) / 64, 256, 0, stream>>>(y2, z2, z2, off, esrc, s2rep, N);
    k_finalize<<<1, 64, 0, stream>>>(s2rep, mean2, inv2, DOUT, invN);
    int nch = N * DOUT / 8;
    k_out<<<(nch + 255) / 256, 256, 0, stream>>>(z2, mean2, inv2, gamma2, beta2,
                                                 (float*)d_out, nch);
}

// Round 8
// 339.306 us; speedup vs baseline: 1.0736x; 1.0736x over previous
//
#include <hip/hip_runtime.h>
#include <hip/hip_bf16.h>
#include <stdint.h>

#define DIN 128
#define DOUT 32
#define NREP 32
#define BKT_SHIFT 9
#define BKT_NODES 512
#define MAXBE 12288

typedef unsigned int uint;
typedef float f32x4 __attribute__((ext_vector_type(4)));
typedef _Float16 f16x8 __attribute__((ext_vector_type(8)));

__device__ __forceinline__ float frelu(float x) { return x > 0.f ? x : 0.f; }

// ---------------- K0: zero bucket counts + stat accumulators ----------------
__global__ void k_zero(uint* __restrict__ bcnt, int nb, float* __restrict__ stats, int nstats) {
    int i = blockIdx.x * blockDim.x + threadIdx.x;
    if (i < nb) bcnt[i] = 0u;
    else if (i < nb + nstats) stats[i - nb] = 0.f;
}

// ---------------- K1 fused: {bucket histogram | weight transpose fp16} ----------------
__global__ __launch_bounds__(256) void k_build1(
    const int* __restrict__ dst, uint* __restrict__ bcnt, int E, int nbuck, int nbE,
    const float* __restrict__ Wrel1, const float* __restrict__ Wroot1,
    const float* __restrict__ Wrel2, const float* __restrict__ Wroot2,
    _Float16* __restrict__ Bt1, _Float16* __restrict__ Bt2) {
    const int bid = blockIdx.x;
    const int t = threadIdx.x;
    if (bid < nbE) {
        __shared__ uint lh[256];
        lh[t] = 0;
        __syncthreads();
        const int base = bid * 8192;
#pragma unroll 8
        for (int i = 0; i < 32; ++i) {
            int e = base + t + 256 * i;
            if (e < E) atomicAdd(&lh[((uint)__builtin_nontemporal_load(&dst[e])) >> BKT_SHIFT], 1u);
        }
        __syncthreads();
        if (t < nbuck && lh[t]) atomicAdd(&bcnt[t], lh[t]);
    } else {
        const int c = bid - nbE;
        const int k = t;
        if (k < 128) {
            if (c < 256) {
                const float* W = (c < 128) ? Wrel1 : Wroot1;
                int cl = c & 127;
                Bt1[c * 128 + k] = (_Float16)W[k * 128 + cl];
            } else {
                int c2 = c - 256;
                const float* W = (c2 < 32) ? Wrel2 : Wroot2;
                int cl = c2 & 31;
                Bt2[c2 * 128 + k] = (_Float16)W[k * 32 + cl];
            }
        }
    }
}

// ---------------- K2: scan bucket counts -> boff, gcur ----------------
__global__ __launch_bounds__(256) void k_bscan(const uint* __restrict__ bcnt,
                                               uint* __restrict__ boff, uint* __restrict__ gcur,
                                               int nbuck, int E) {
    __shared__ uint ps[256];
    const int t = threadIdx.x;
    uint v = (t < nbuck) ? bcnt[t] : 0u;
    ps[t] = v;
    __syncthreads();
    for (int o = 1; o < 256; o <<= 1) {
        uint u = (t >= o) ? ps[t - o] : 0u;
        __syncthreads();
        ps[t] += u;
        __syncthreads();
    }
    if (t < nbuck) {
        uint ex = ps[t] - v;
        boff[t] = ex;
        gcur[t] = ex;
    }
    if (t == 0) boff[nbuck] = (uint)E;
}

// ---------------- K3 fused: {edge partition | GEMM1} ----------------
// blocks [0,nbE): partition edges -> gbuf. blocks [nbE, nbE+nb64*4): GEMM1
// y1 = x@Wrel1 (fp16), z1 = x@Wroot1 + brel1 (fp16), row-major.
__global__ __launch_bounds__(256) void k_part_gemm(
    const int* __restrict__ src, const int* __restrict__ dst,
    uint* __restrict__ gcur, uint* __restrict__ gbuf, int E, int nbuck, int nbE,
    const float* __restrict__ A, const _Float16* __restrict__ Bt,
    const float* __restrict__ bias,
    _Float16* __restrict__ Y, _Float16* __restrict__ Z, int N) {
    __shared__ __align__(16) char smem[32768];
    const int tid = threadIdx.x;
    const int bid = blockIdx.x;

    if (bid < nbE) {
        // ---- partition role ----
        uint* lh = (uint*)smem;
        uint* lb = lh + 256;
        uint* lc = lb + 256;
        lh[tid] = 0;
        lc[tid] = 0;
        __syncthreads();
        const int base = bid * 8192;
#pragma unroll 8
        for (int i = 0; i < 32; ++i) {
            int e = base + tid + 256 * i;
            if (e < E) atomicAdd(&lh[((uint)__builtin_nontemporal_load(&dst[e])) >> BKT_SHIFT], 1u);
        }
        __syncthreads();
        if (tid < nbuck && lh[tid]) lb[tid] = atomicAdd(&gcur[tid], lh[tid]);
        __syncthreads();
#pragma unroll 8
        for (int i = 0; i < 32; ++i) {
            int e = base + tid + 256 * i;
            if (e < E) {
                uint d = (uint)__builtin_nontemporal_load(&dst[e]);
                uint s = (uint)__builtin_nontemporal_load(&src[e]);
                uint b = d >> BKT_SHIFT;
                uint r = atomicAdd(&lc[b], 1u);
                gbuf[lb[b] + r] = ((d & (BKT_NODES - 1)) << 17) | s;
            }
        }
        return;
    }

    // ---- GEMM1 role ----
    const int q = bid - nbE;
    const int rowBase = (q >> 2) * 64;
    const int colBase = (q & 3) * 64;

#pragma unroll
    for (int i = 0; i < 8; ++i) {
        int f = tid + 256 * i;
        int row = f >> 5, c4 = f & 31;
        int grow = rowBase + row;
        float4 v = make_float4(0.f, 0.f, 0.f, 0.f);
        if (grow < N) v = *(const float4*)&A[(size_t)grow * DIN + c4 * 4];
        union { short4 s; _Float16 h[4]; } u;
        u.h[0] = (_Float16)v.x; u.h[1] = (_Float16)v.y;
        u.h[2] = (_Float16)v.z; u.h[3] = (_Float16)v.w;
        int off = row * 256 + ((c4 * 8) ^ ((row & 7) << 4));
        *(short4*)(smem + off) = u.s;
    }
#pragma unroll
    for (int i = 0; i < 4; ++i) {
        int f = tid + 256 * i;
        int row = f >> 4, sl = f & 15;
        f16x8 v = *(const f16x8*)&Bt[(size_t)(colBase + row) * 128 + sl * 8];
        int off = row * 256 + ((sl * 16) ^ ((row & 7) << 4));
        *(f16x8*)(smem + 16384 + off) = v;
    }
    __syncthreads();

    const int lane = tid & 63;
    const int w = tid >> 6;
    const int wrow = (w >> 1) * 32;
    const int wcol = (w & 1) * 32;
    const int lr = lane & 15;
    const int lk = lane >> 4;

    f32x4 acc[2][2] = {};
#pragma unroll
    for (int s = 0; s < 4; ++s) {
        f16x8 a[2], b[2];
#pragma unroll
        for (int m = 0; m < 2; ++m) {
            int row = wrow + m * 16 + lr;
            int off = row * 256 + (((s * 64) + lk * 16) ^ ((row & 7) << 4));
            a[m] = *(const f16x8*)(smem + off);
        }
#pragma unroll
        for (int n = 0; n < 2; ++n) {
            int col = wcol + n * 16 + lr;
            int off = col * 256 + (((s * 64) + lk * 16) ^ ((col & 7) << 4));
            b[n] = *(const f16x8*)(smem + 16384 + off);
        }
#pragma unroll
        for (int m = 0; m < 2; ++m)
#pragma unroll
            for (int n = 0; n < 2; ++n)
                acc[m][n] = __builtin_amdgcn_mfma_f32_16x16x32_f16(a[m], b[n], acc[m][n], 0, 0, 0);
    }

    __syncthreads();
    float* Cs = (float*)smem;
#pragma unroll
    for (int m = 0; m < 2; ++m)
#pragma unroll
        for (int n = 0; n < 2; ++n) {
            int r0 = wrow + m * 16 + (lane >> 4) * 4;
            int c = wcol + n * 16 + (lane & 15);
#pragma unroll
            for (int j = 0; j < 4; ++j) Cs[(r0 + j) * 68 + c] = acc[m][n][j];
        }
    __syncthreads();

    {
        int row = tid >> 2, cq = tid & 3;
        int grow = rowBase + row;
        if (grow < N) {
            const int cb = row * 68 + cq * 16;
            f32x4 t0 = *(const f32x4*)&Cs[cb + 0];
            f32x4 t1 = *(const f32x4*)&Cs[cb + 4];
            f32x4 t2 = *(const f32x4*)&Cs[cb + 8];
            f32x4 t3 = *(const f32x4*)&Cs[cb + 12];
            int gc0 = colBase + cq * 16;
            _Float16* dstp;
            int dcol;
            if (gc0 < DIN) {
                dstp = Y; dcol = gc0;
            } else {
                dstp = Z; dcol = gc0 - DIN;
                f32x4 b0 = *(const f32x4*)&bias[dcol + 0];
                f32x4 b1 = *(const f32x4*)&bias[dcol + 4];
                f32x4 b2 = *(const f32x4*)&bias[dcol + 8];
                f32x4 b3 = *(const f32x4*)&bias[dcol + 12];
                t0 += b0; t1 += b1; t2 += b2; t3 += b3;
            }
            f16x8 h0, h1;
            h0[0] = (_Float16)t0.x; h0[1] = (_Float16)t0.y; h0[2] = (_Float16)t0.z; h0[3] = (_Float16)t0.w;
            h0[4] = (_Float16)t1.x; h0[5] = (_Float16)t1.y; h0[6] = (_Float16)t1.z; h0[7] = (_Float16)t1.w;
            h1[0] = (_Float16)t2.x; h1[1] = (_Float16)t2.y; h1[2] = (_Float16)t2.z; h1[3] = (_Float16)t2.w;
            h1[4] = (_Float16)t3.x; h1[5] = (_Float16)t3.y; h1[6] = (_Float16)t3.z; h1[7] = (_Float16)t3.w;
            *(f16x8*)&dstp[(size_t)grow * DIN + dcol] = h0;
            *(f16x8*)&dstp[(size_t)grow * DIN + dcol + 8] = h1;
        }
    }
}

// ---------------- K4: per-bucket local CSR: off + esrc ----------------
__global__ __launch_bounds__(256) void k_csr(const uint* __restrict__ boff,
                                             const uint* __restrict__ gbuf,
                                             uint* __restrict__ off, uint* __restrict__ esrc,
                                             int N, int E, int nbuck) {
    __shared__ uint ed[MAXBE];
    __shared__ uint lh[BKT_NODES];
    __shared__ uint lsc[BKT_NODES];
    __shared__ uint ps[256];
    const int b = blockIdx.x, t = threadIdx.x;
    const uint bb = boff[b];
    int cnt = (int)(boff[b + 1] - bb);
    if (cnt > MAXBE) cnt = MAXBE;
    for (int i = t; i < cnt; i += 256) ed[i] = __builtin_nontemporal_load(&gbuf[bb + i]);
    lh[t] = 0;
    lh[t + 256] = 0;
    __syncthreads();
    for (int i = t; i < cnt; i += 256) atomicAdd(&lh[ed[i] >> 17], 1u);
    __syncthreads();
    const uint v0 = lh[2 * t], v1 = lh[2 * t + 1];
    ps[t] = v0 + v1;
    __syncthreads();
    for (int o = 1; o < 256; o <<= 1) {
        uint u = (t >= o) ? ps[t - o] : 0u;
        __syncthreads();
        ps[t] += u;
        __syncthreads();
    }
    const uint ex = ps[t] - (v0 + v1);
    lsc[2 * t] = ex;
    lsc[2 * t + 1] = ex + v0;
    const int n0 = b << BKT_SHIFT;
    if (n0 + 2 * t < N) off[n0 + 2 * t] = bb + ex;
    if (n0 + 2 * t + 1 < N) off[n0 + 2 * t + 1] = bb + ex + v0;
    if (b == nbuck - 1 && t == 0) off[N] = (uint)E;
    __syncthreads();
    for (int i = t; i < cnt; i += 256) {
        uint p = ed[i];
        uint r = atomicAdd(&lsc[p >> 17], 1u);
        esrc[bb + r] = p & 0x1FFFFu;
    }
}

// ---------------- GEMM2 (templated path kept for NORM+fp16 A) ----------------
template <int WC>
__global__ __launch_bounds__(256) void k_gemm2(
    const _Float16* __restrict__ A, const _Float16* __restrict__ Bt,
    const float* __restrict__ bias,
    const float* __restrict__ mean, const float* __restrict__ inv,
    const float* __restrict__ gamma, const float* __restrict__ beta,
    _Float16* __restrict__ Y, _Float16* __restrict__ Z, int N) {
    __shared__ __align__(16) char smem[32768];
    const int tid = threadIdx.x;
    const int rowBase = blockIdx.x * 64;
    const int colBase = blockIdx.y * 64;

#pragma unroll
    for (int i = 0; i < 4; ++i) {
        int f = tid + 256 * i;
        int row = f >> 4, sl = f & 15;
        int grow = rowBase + row;
        f16x8 hv = {};
        if (grow < N) {
            f16x8 a = *(const f16x8*)&A[(size_t)grow * DIN + sl * 8];
            int k = sl * 8;
            f32x4 m0 = *(const f32x4*)&mean[k],  m1 = *(const f32x4*)&mean[k + 4];
            f32x4 i0 = *(const f32x4*)&inv[k],   i1 = *(const f32x4*)&inv[k + 4];
            f32x4 g0 = *(const f32x4*)&gamma[k], g1 = *(const f32x4*)&gamma[k + 4];
            f32x4 b0 = *(const f32x4*)&beta[k],  b1 = *(const f32x4*)&beta[k + 4];
#pragma unroll
            for (int j = 0; j < 4; ++j) {
                float v = frelu(((float)a[j] - m0[j]) * i0[j] * g0[j] + b0[j]);
                hv[j] = (_Float16)v;
            }
#pragma unroll
            for (int j = 0; j < 4; ++j) {
                float v = frelu(((float)a[4 + j] - m1[j]) * i1[j] * g1[j] + b1[j]);
                hv[4 + j] = (_Float16)v;
            }
        }
        int off = row * 256 + ((sl * 16) ^ ((row & 7) << 4));
        *(f16x8*)(smem + off) = hv;
    }
#pragma unroll
    for (int i = 0; i < 4; ++i) {
        int f = tid + 256 * i;
        int row = f >> 4, sl = f & 15;
        f16x8 v = *(const f16x8*)&Bt[(size_t)(colBase + row) * 128 + sl * 8];
        int off = row * 256 + ((sl * 16) ^ ((row & 7) << 4));
        *(f16x8*)(smem + 16384 + off) = v;
    }
    __syncthreads();

    const int lane = tid & 63;
    const int w = tid >> 6;
    const int wrow = (w >> 1) * 32;
    const int wcol = (w & 1) * 32;
    const int lr = lane & 15;
    const int lk = lane >> 4;

    f32x4 acc[2][2] = {};
#pragma unroll
    for (int s = 0; s < 4; ++s) {
        f16x8 a[2], b[2];
#pragma unroll
        for (int m = 0; m < 2; ++m) {
            int row = wrow + m * 16 + lr;
            int off = row * 256 + (((s * 64) + lk * 16) ^ ((row & 7) << 4));
            a[m] = *(const f16x8*)(smem + off);
        }
#pragma unroll
        for (int n = 0; n < 2; ++n) {
            int col = wcol + n * 16 + lr;
            int off = col * 256 + (((s * 64) + lk * 16) ^ ((col & 7) << 4));
            b[n] = *(const f16x8*)(smem + 16384 + off);
        }
#pragma unroll
        for (int m = 0; m < 2; ++m)
#pragma unroll
            for (int n = 0; n < 2; ++n)
                acc[m][n] = __builtin_amdgcn_mfma_f32_16x16x32_f16(a[m], b[n], acc[m][n], 0, 0, 0);
    }

    __syncthreads();
    float* Cs = (float*)smem;
#pragma unroll
    for (int m = 0; m < 2; ++m)
#pragma unroll
        for (int n = 0; n < 2; ++n) {
            int r0 = wrow + m * 16 + (lane >> 4) * 4;
            int c = wcol + n * 16 + (lane & 15);
#pragma unroll
            for (int j = 0; j < 4; ++j) Cs[(r0 + j) * 68 + c] = acc[m][n][j];
        }
    __syncthreads();

    {
        int row = tid >> 2, cq = tid & 3;
        int grow = rowBase + row;
        if (grow < N) {
            const int cb = row * 68 + cq * 16;
            f32x4 t0 = *(const f32x4*)&Cs[cb + 0];
            f32x4 t1 = *(const f32x4*)&Cs[cb + 4];
            f32x4 t2 = *(const f32x4*)&Cs[cb + 8];
            f32x4 t3 = *(const f32x4*)&Cs[cb + 12];
            int gc0 = colBase + cq * 16;
            _Float16* dstp;
            int dcol;
            if (gc0 < WC) {
                dstp = Y; dcol = gc0;
            } else {
                dstp = Z; dcol = gc0 - WC;
                f32x4 b0 = *(const f32x4*)&bias[dcol + 0];
                f32x4 b1 = *(const f32x4*)&bias[dcol + 4];
                f32x4 b2 = *(const f32x4*)&bias[dcol + 8];
                f32x4 b3 = *(const f32x4*)&bias[dcol + 12];
                t0 += b0; t1 += b1; t2 += b2; t3 += b3;
            }
            f16x8 h0, h1;
            h0[0] = (_Float16)t0.x; h0[1] = (_Float16)t0.y; h0[2] = (_Float16)t0.z; h0[3] = (_Float16)t0.w;
            h0[4] = (_Float16)t1.x; h0[5] = (_Float16)t1.y; h0[6] = (_Float16)t1.z; h0[7] = (_Float16)t1.w;
            h1[0] = (_Float16)t2.x; h1[1] = (_Float16)t2.y; h1[2] = (_Float16)t2.z; h1[3] = (_Float16)t2.w;
            h1[4] = (_Float16)t3.x; h1[5] = (_Float16)t3.y; h1[6] = (_Float16)t3.z; h1[7] = (_Float16)t3.w;
            *(f16x8*)&dstp[(size_t)grow * WC + dcol] = h0;
            *(f16x8*)&dstp[(size_t)grow * WC + dcol + 8] = h1;
        }
    }
}

// ---------------- Aggregation (row-major fp16): h[n] = sum_e y[esrc[e]] + z[n] ----------------
template <int DIMS, int IT>
__global__ __launch_bounds__(256) void k_agg(
    const _Float16* __restrict__ y, const _Float16* z, _Float16* h,
    const uint* __restrict__ off, const uint* __restrict__ esrc,
    float* __restrict__ gstat, int N) {
    constexpr int TPN = DIMS / 8;
    constexpr int G = 256 / TPN;
    const int tid = threadIdx.x;
    const int c8 = tid & (TPN - 1);
    const int g = tid / TPN;
    const int col0 = c8 * 8;
    const int base = blockIdx.x * (G * IT);
    float ssum[8] = {0, 0, 0, 0, 0, 0, 0, 0};
    float ssq[8] = {0, 0, 0, 0, 0, 0, 0, 0};

    for (int it = 0; it < IT; ++it) {
        const int n = base + it * G + g;
        if (n < N) {
            const uint beg = off[n], end = off[n + 1];
            float acc[8] = {0, 0, 0, 0, 0, 0, 0, 0};
            uint e = beg;
            for (; e + 4 <= end; e += 4) {
                const uint s0 = esrc[e], s1 = esrc[e + 1];
                const uint s2 = esrc[e + 2], s3 = esrc[e + 3];
                const f16x8 a0 = *(const f16x8*)&y[(size_t)s0 * DIMS + col0];
                const f16x8 a1 = *(const f16x8*)&y[(size_t)s1 * DIMS + col0];
                const f16x8 a2 = *(const f16x8*)&y[(size_t)s2 * DIMS + col0];
                const f16x8 a3 = *(const f16x8*)&y[(size_t)s3 * DIMS + col0];
#pragma unroll
                for (int j = 0; j < 8; ++j)
                    acc[j] += ((float)a0[j] + (float)a1[j]) + ((float)a2[j] + (float)a3[j]);
            }
            for (; e < end; ++e) {
                const uint s0 = esrc[e];
                const f16x8 a0 = *(const f16x8*)&y[(size_t)s0 * DIMS + col0];
#pragma unroll
                for (int j = 0; j < 8; ++j) acc[j] += (float)a0[j];
            }
            const size_t idx = (size_t)n * DIMS + col0;
            const f16x8 zz = __builtin_nontemporal_load((const f16x8*)&z[idx]);
            float hv[8];
            f16x8 hs;
#pragma unroll
            for (int j = 0; j < 8; ++j) {
                hv[j] = acc[j] + (float)zz[j];
                hs[j] = (_Float16)hv[j];
            }
            __builtin_nontemporal_store(hs, (f16x8*)&h[idx]);
#pragma unroll
            for (int j = 0; j < 8; ++j) {
                ssum[j] += hv[j];
                ssq[j] += hv[j] * hv[j];
            }
        }
    }

    __shared__ f32x4 redA[256], redB[256], redC[256], redD[256];
    redA[tid] = (f32x4){ssum[0], ssum[1], ssum[2], ssum[3]};
    redB[tid] = (f32x4){ssum[4], ssum[5], ssum[6], ssum[7]};
    redC[tid] = (f32x4){ssq[0], ssq[1], ssq[2], ssq[3]};
    redD[tid] = (f32x4){ssq[4], ssq[5], ssq[6], ssq[7]};
    __syncthreads();
    for (int st = G / 2; st >= 1; st >>= 1) {
        if (g < st) {
            redA[tid] += redA[tid + st * TPN];
            redB[tid] += redB[tid + st * TPN];
            redC[tid] += redC[tid + st * TPN];
            redD[tid] += redD[tid + st * TPN];
        }
        __syncthreads();
    }
    if (g == 0) {
        float* gs = gstat + (blockIdx.x & (NREP - 1)) * (2 * DIMS);
        f32x4 s0 = redA[c8], s1 = redB[c8], q0 = redC[c8], q1 = redD[c8];
        unsafeAtomicAdd(&gs[col0 + 0], s0.x);
        unsafeAtomicAdd(&gs[col0 + 1], s0.y);
        unsafeAtomicAdd(&gs[col0 + 2], s0.z);
        unsafeAtomicAdd(&gs[col0 + 3], s0.w);
        unsafeAtomicAdd(&gs[col0 + 4], s1.x);
        unsafeAtomicAdd(&gs[col0 + 5], s1.y);
        unsafeAtomicAdd(&gs[col0 + 6], s1.z);
        unsafeAtomicAdd(&gs[col0 + 7], s1.w);
        unsafeAtomicAdd(&gs[DIMS + col0 + 0], q0.x);
        unsafeAtomicAdd(&gs[DIMS + col0 + 1], q0.y);
        unsafeAtomicAdd(&gs[DIMS + col0 + 2], q0.z);
        unsafeAtomicAdd(&gs[DIMS + col0 + 3], q0.w);
        unsafeAtomicAdd(&gs[DIMS + col0 + 4], q1.x);
        unsafeAtomicAdd(&gs[DIMS + col0 + 5], q1.y);
        unsafeAtomicAdd(&gs[DIMS + col0 + 6], q1.z);
        unsafeAtomicAdd(&gs[DIMS + col0 + 7], q1.w);
    }
}

// ---------------- finalize BN stats from NREP replicas ----------------
__global__ void k_finalize(const float* __restrict__ rep, float* __restrict__ mean,
                           float* __restrict__ inv, int C, float invN) {
    int c = threadIdx.x;
    if (c < C) {
        float s = 0.f, q = 0.f;
        for (int r = 0; r < NREP; ++r) {
            s += rep[r * 2 * C + c];
            q += rep[r * 2 * C + C + c];
        }
        float m = s * invN;
        float v = q * invN - m * m;
        mean[c] = m;
        inv[c] = rsqrtf(v + 1e-5f);
    }
}

// ---------------- final BN+relu elementwise (h2 fp16 -> out fp32) ----------------
__global__ void k_out(const _Float16* __restrict__ h2, const float* __restrict__ mean,
                      const float* __restrict__ inv, const float* __restrict__ gamma,
                      const float* __restrict__ beta, float* __restrict__ out, int nch) {
    int i = blockIdx.x * blockDim.x + threadIdx.x;
    if (i < nch) {
        int c = (i & 3) * 8;
        f16x8 hv = *(const f16x8*)&h2[(size_t)i * 8];
        f32x4 m0 = *(const f32x4*)&mean[c],  m1 = *(const f32x4*)&mean[c + 4];
        f32x4 i0 = *(const f32x4*)&inv[c],   i1 = *(const f32x4*)&inv[c + 4];
        f32x4 g0 = *(const f32x4*)&gamma[c], g1 = *(const f32x4*)&gamma[c + 4];
        f32x4 b0 = *(const f32x4*)&beta[c],  b1 = *(const f32x4*)&beta[c + 4];
        f32x4 o0, o1;
#pragma unroll
        for (int j = 0; j < 4; ++j) o0[j] = frelu(((float)hv[j] - m0[j]) * i0[j] * g0[j] + b0[j]);
#pragma unroll
        for (int j = 0; j < 4; ++j) o1[j] = frelu(((float)hv[4 + j] - m1[j]) * i1[j] * g1[j] + b1[j]);
        *(f32x4*)&out[(size_t)i * 8] = o0;
        *(f32x4*)&out[(size_t)i * 8 + 4] = o1;
    }
}

extern "C" void kernel_launch(void* const* d_in, const int* in_sizes, int n_in,
                              void* d_out, int out_size, void* d_ws, size_t ws_size,
                              hipStream_t stream) {
    const float* x      = (const float*)d_in[0];
    const int*   eidx   = (const int*)d_in[1];
    const float* Wrel1  = (const float*)d_in[2];
    const float* brel1  = (const float*)d_in[3];
    const float* Wroot1 = (const float*)d_in[4];
    const float* gamma1 = (const float*)d_in[5];
    const float* beta1  = (const float*)d_in[6];
    const float* Wrel2  = (const float*)d_in[7];
    const float* brel2  = (const float*)d_in[8];
    const float* Wroot2 = (const float*)d_in[9];
    const float* gamma2 = (const float*)d_in[10];
    const float* beta2  = (const float*)d_in[11];

    const int N = in_sizes[0] / DIN;
    const int E = in_sizes[1] / 2;
    const int* src = eidx;
    const int* dst = eidx + E;
    const int nbuck = (N + BKT_NODES - 1) >> BKT_SHIFT;

    char* p = (char*)d_ws;
    auto alloc = [&](size_t bytes) {
        void* r = (void*)p;
        p += (bytes + 255) & ~(size_t)255;
        return r;
    };
    uint*      bcnt = (uint*)alloc(256 * 4);
    uint*      boff = (uint*)alloc(257 * 4);
    uint*      gcur = (uint*)alloc(256 * 4);
    uint*      gbuf = (uint*)alloc((size_t)E * 4);
    uint*      esrc = (uint*)alloc((size_t)E * 4);
    uint*      off  = (uint*)alloc((size_t)(N + 1) * 4);
    _Float16*  Bt1  = (_Float16*)alloc(256 * 128 * 2);
    _Float16*  Bt2  = (_Float16*)alloc(64 * 128 * 2);
    _Float16*  y1   = (_Float16*)alloc((size_t)N * DIN * 2);
    _Float16*  z1   = (_Float16*)alloc((size_t)N * DIN * 2);   // h1 aliases z1
    _Float16*  y2   = (_Float16*)alloc((size_t)N * DOUT * 2);
    _Float16*  z2   = (_Float16*)alloc((size_t)N * DOUT * 2);  // h2 aliases z2
    float*     stats = (float*)alloc((size_t)(NREP * 2 * DIN + NREP * 2 * DOUT + 2 * DIN + 2 * DOUT) * 4);
    float* s1rep = stats;
    float* s2rep = stats + NREP * 2 * DIN;
    float* mean1 = s2rep + NREP * 2 * DOUT;
    float* inv1  = mean1 + DIN;
    float* mean2 = inv1 + DIN;
    float* inv2  = mean2 + DOUT;

    const float invN = 1.f / (float)N;
    const int nstats = NREP * 2 * DIN + NREP * 2 * DOUT;
    const int nbE = (E + 8191) / 8192;
    const int nb64 = (N + 63) / 64;

    int nz = 256 + nstats;
    k_zero<<<(nz + 255) / 256, 256, 0, stream>>>(bcnt, 256, stats, nstats);
    // fused {bhist | prepw}
    k_build1<<<nbE + 320, 256, 0, stream>>>(dst, bcnt, E, nbuck, nbE,
                                            Wrel1, Wroot1, Wrel2, Wroot2, Bt1, Bt2);
    k_bscan<<<1, 256, 0, stream>>>(bcnt, boff, gcur, nbuck, E);
    // fused {part | GEMM1}
    k_part_gemm<<<nbE + nb64 * 4, 256, 0, stream>>>(src, dst, gcur, gbuf, E, nbuck, nbE,
                                                    x, Bt1, brel1, y1, z1, N);
    k_csr<<<nbuck, 256, 0, stream>>>(boff, gbuf, off, esrc, N, E, nbuck);
    // agg1 + stats (h1 -> z1): 32 nodes/block, grid 3125
    k_agg<DIN, 2><<<(N + 31) / 32, 256, 0, stream>>>(y1, z1, z1, off, esrc, s1rep, N);
    k_finalize<<<1, DIN, 0, stream>>>(s1rep, mean1, inv1, DIN, invN);
    // GEMM2 with fused BN1+relu
    k_gemm2<DOUT><<<dim3(nb64, 1), 256, 0, stream>>>(
        z1, Bt2, brel2, mean1, inv1, gamma1, beta1, y2, z2, N);
    // agg2 + stats (h2 -> z2)
    k_agg<DOUT, 1><<<(N + 63) / 64, 256, 0, stream>>>(y2, z2, z2, off, esrc, s2rep, N);
    k_finalize<<<1, 64, 0, stream>>>(s2rep, mean2, inv2, DOUT, invN);
    int nch = N * DOUT / 8;
    k_out<<<(nch + 255) / 256, 256, 0, stream>>>(z2, mean2, inv2, gamma2, beta2,
                                                 (float*)d_out, nch);
}